// Round 1
// baseline (1128.366 us; speedup 1.0000x reference)
//
#include <hip/hip_runtime.h>
#include <hip/hip_bf16.h>
#include <stdint.h>

#define NF 64
#define NC 40

// ---------------------------------------------------------------------------
// Detect whether edge_index was uploaded as int32 or int64.
// For int64 (values in [0, 1e5)), every odd 32-bit word is 0.
// For int32 random indices, odd words are nonzero w.h.p.
// flag = 1 -> int32, flag = 0 -> int64. Single block, no pre-zero needed.
// ---------------------------------------------------------------------------
__global__ void detect_dtype_kernel(const unsigned int* __restrict__ p, int* __restrict__ flag,
                                    int n_check) {
    __shared__ int s_any;
    if (threadIdx.x == 0) s_any = 0;
    __syncthreads();
    int any = 0;
    for (int i = threadIdx.x; i < n_check; i += blockDim.x) {
        if (p[2 * i + 1] != 0u) any = 1;
    }
    if (any) atomicOr(&s_any, 1);
    __syncthreads();
    if (threadIdx.x == 0) *flag = s_any;
}

__device__ __forceinline__ long long load_idx(const void* p, long long i, int is32) {
    if (is32) return (long long)((const int*)p)[i];
    return ((const long long*)p)[i];
}

// deg[i] = 1.0 (self loop)
__global__ void init_deg_kernel(float* __restrict__ deg, int N) {
    int i = blockIdx.x * blockDim.x + threadIdx.x;
    if (i < N) deg[i] = 1.0f;
}

// deg[col[e]] += 1
__global__ void count_deg_kernel(const void* __restrict__ ei, float* __restrict__ deg,
                                 const int* __restrict__ flag, long long E) {
    long long e = (long long)blockIdx.x * blockDim.x + threadIdx.x;
    if (e >= E) return;
    int is32 = *flag;
    long long c = load_idx(ei, E + e, is32);
    atomicAdd(&deg[c], 1.0f);
}

// dinv[i] = rsqrt(deg[i])   (deg >= 1 always due to self loop)
__global__ void dinv_kernel(float* __restrict__ deg, int N) {
    int i = blockIdx.x * blockDim.x + threadIdx.x;
    if (i < N) {
        float d = deg[i];
        deg[i] = (d > 0.0f) ? rsqrtf(d) : 0.0f;
    }
}

// hout[i][f] = dinv[i]^2 * hin[i][f]   (self-loop contribution, initializes hout)
__global__ void self_loop_kernel(const float* __restrict__ hin, float* __restrict__ hout,
                                 const float* __restrict__ dinv, long long NF_total) {
    long long t = (long long)blockIdx.x * blockDim.x + threadIdx.x;
    if (t >= NF_total) return;
    long long node = t >> 6;
    float d = dinv[node];
    hout[t] = d * d * hin[t];
}

// One wave (64 lanes) per edge; lane = feature index.
// hout[col][lane] += dinv[row]*dinv[col] * hin[row][lane]
__global__ void scatter_kernel(const void* __restrict__ ei, const float* __restrict__ hin,
                               const float* __restrict__ dinv, float* __restrict__ hout,
                               const int* __restrict__ flag, long long E) {
    long long t = (long long)blockIdx.x * blockDim.x + threadIdx.x;
    long long e = t >> 6;
    int lane = (int)(t & 63);
    if (e >= E) return;
    int is32 = *flag;
    long long r = load_idx(ei, e, is32);
    long long c = load_idx(ei, E + e, is32);
    float w = dinv[r] * dinv[c];
    float v = w * hin[r * NF + lane];
    atomicAdd(&hout[c * NF + lane], v);
}

// logits = h @ W^T + b ; relu ; log_softmax. One thread per node, W in LDS.
__global__ void classify_kernel(const float* __restrict__ h, const float* __restrict__ W,
                                const float* __restrict__ b, float* __restrict__ out, int N) {
    __shared__ float4 sW[NC * (NF / 4)];
    __shared__ float sb[NC];
    for (int i = threadIdx.x; i < NC * (NF / 4); i += blockDim.x)
        sW[i] = ((const float4*)W)[i];
    if (threadIdx.x < NC) sb[threadIdx.x] = b[threadIdx.x];
    __syncthreads();

    int node = blockIdx.x * blockDim.x + threadIdx.x;
    if (node >= N) return;

    float4 hv[NF / 4];
    const float4* hp = (const float4*)(h + (long long)node * NF);
#pragma unroll
    for (int i = 0; i < NF / 4; ++i) hv[i] = hp[i];

    float lg[NC];
    float mx = 0.0f;  // after relu, all values >= 0
#pragma unroll
    for (int c = 0; c < NC; ++c) {
        float4 a = {0.f, 0.f, 0.f, 0.f};
#pragma unroll
        for (int i = 0; i < NF / 4; ++i) {
            float4 w = sW[c * (NF / 4) + i];
            a.x += w.x * hv[i].x;
            a.y += w.y * hv[i].y;
            a.z += w.z * hv[i].z;
            a.w += w.w * hv[i].w;
        }
        float l = (a.x + a.y) + (a.z + a.w) + sb[c];
        l = fmaxf(l, 0.0f);
        lg[c] = l;
        mx = fmaxf(mx, l);
    }
    float s = 0.0f;
#pragma unroll
    for (int c = 0; c < NC; ++c) s += __expf(lg[c] - mx);
    float lse = mx + __logf(s);

    float* op = out + (long long)node * NC;
#pragma unroll
    for (int c = 0; c < NC; ++c) op[c] = lg[c] - lse;
}

extern "C" void kernel_launch(void* const* d_in, const int* in_sizes, int n_in,
                              void* d_out, int out_size, void* d_ws, size_t ws_size,
                              hipStream_t stream) {
    const float* x = (const float*)d_in[0];
    const void* ei = d_in[1];
    const float* W = (const float*)d_in[2];
    const float* b = (const float*)d_in[3];
    float* out = (float*)d_out;

    const int N = in_sizes[0] / NF;          // 100000
    const long long E = in_sizes[1] / 2;     // 1250000

    // workspace layout
    size_t off = 0;
    int* flag = (int*)((char*)d_ws + off);
    off = 256;
    float* dinv = (float*)((char*)d_ws + off);
    off += (size_t)N * sizeof(float);
    off = (off + 255) & ~(size_t)255;
    float* h1 = (float*)((char*)d_ws + off);
    off += (size_t)N * NF * sizeof(float);
    float* h2 = (float*)((char*)d_ws + off);
    off += (size_t)N * NF * sizeof(float);
    if (off > ws_size) return;  // workspace too small; bail (will fail validation)

    const int B = 256;

    // 0. dtype detection
    int n_check = (int)((E < 65536) ? E : 65536);
    detect_dtype_kernel<<<1, 256, 0, stream>>>((const unsigned int*)ei, flag, n_check);

    // 1. degrees -> dinv
    init_deg_kernel<<<(N + B - 1) / B, B, 0, stream>>>(dinv, N);
    count_deg_kernel<<<(int)((E + B - 1) / B), B, 0, stream>>>(ei, dinv, flag, E);
    dinv_kernel<<<(N + B - 1) / B, B, 0, stream>>>(dinv, N);

    // 2. K=3 propagation hops (ping-pong; never mutate x)
    long long NFt = (long long)N * NF;
    int gridNF = (int)((NFt + B - 1) / B);
    long long Ethreads = E * 64;
    int gridE = (int)((Ethreads + B - 1) / B);

    const float* hin = x;
    float* bufs[3] = {h1, h2, h1};
    for (int k = 0; k < 3; ++k) {
        float* hout = bufs[k];
        self_loop_kernel<<<gridNF, B, 0, stream>>>(hin, hout, dinv, NFt);
        scatter_kernel<<<gridE, B, 0, stream>>>(ei, hin, dinv, hout, flag, E);
        hin = hout;
    }

    // 3. classify: linear + relu + log_softmax
    classify_kernel<<<(N + B - 1) / B, B, 0, stream>>>(hin, W, b, out, N);
}

// Round 2
// 598.515 us; speedup vs baseline: 1.8853x; 1.8853x over previous
//
#include <hip/hip_runtime.h>
#include <hip/hip_bf16.h>
#include <stdint.h>

#define NF 64
#define NC 40
#define SCAN_BLK 1024  // elements scanned per block (256 threads x 4)

// ---------------------------------------------------------------------------
// Detect whether edge_index was uploaded as int32 or int64.
// For int64 (values < 2^31), every odd 32-bit word is 0.
// flag = 1 -> int32, flag = 0 -> int64.
// ---------------------------------------------------------------------------
__global__ void detect_dtype_kernel(const unsigned int* __restrict__ p, int* __restrict__ flag,
                                    int n_check) {
    __shared__ int s_any;
    if (threadIdx.x == 0) s_any = 0;
    __syncthreads();
    int any = 0;
    for (int i = threadIdx.x; i < n_check; i += blockDim.x) {
        if (p[2 * i + 1] != 0u) any = 1;
    }
    if (any) atomicOr(&s_any, 1);
    __syncthreads();
    if (threadIdx.x == 0) *flag = s_any;
}

__device__ __forceinline__ long long load_idx(const void* p, long long i, int is32) {
    if (is32) return (long long)((const int*)p)[i];
    return ((const long long*)p)[i];
}

__global__ void zero_cnt_kernel(int* __restrict__ cnt, int N) {
    int i = blockIdx.x * blockDim.x + threadIdx.x;
    if (i < N) cnt[i] = 0;
}

// cnt[col[e]] += 1  (in-degree, without self loop)
__global__ void count_kernel(const void* __restrict__ ei, int* __restrict__ cnt,
                             const int* __restrict__ flag, long long E) {
    long long e = (long long)blockIdx.x * blockDim.x + threadIdx.x;
    if (e >= E) return;
    int is32 = *flag;
    int c = (int)load_idx(ei, E + e, is32);
    atomicAdd(&cnt[c], 1);
}

// Per-block exclusive scan of cnt into row_ptr (block-local), block totals -> aux
__global__ void scanA_kernel(const int* __restrict__ cnt, int* __restrict__ row_ptr,
                             int* __restrict__ aux, int N) {
    __shared__ int sd[256];
    int t = threadIdx.x;
    int base = blockIdx.x * SCAN_BLK + t * 4;
    int v[4];
    int s = 0;
#pragma unroll
    for (int j = 0; j < 4; ++j) {
        v[j] = (base + j < N) ? cnt[base + j] : 0;
        s += v[j];
    }
    sd[t] = s;
    __syncthreads();
#pragma unroll
    for (int off = 1; off < 256; off <<= 1) {
        int a = (t >= off) ? sd[t - off] : 0;
        __syncthreads();
        sd[t] += a;
        __syncthreads();
    }
    int run = sd[t] - s;  // exclusive offset of this thread within block
#pragma unroll
    for (int j = 0; j < 4; ++j) {
        if (base + j < N) row_ptr[base + j] = run;
        run += v[j];
    }
    if (t == 255) aux[blockIdx.x] = sd[255];
}

// Exclusive scan of block totals (nb <= 128), single block of 128 threads
__global__ void scanB_kernel(int* __restrict__ aux, int nb) {
    __shared__ int sd[128];
    int t = threadIdx.x;
    int v = (t < nb) ? aux[t] : 0;
    sd[t] = v;
    __syncthreads();
#pragma unroll
    for (int off = 1; off < 128; off <<= 1) {
        int a = (t >= off) ? sd[t - off] : 0;
        __syncthreads();
        sd[t] += a;
        __syncthreads();
    }
    if (t < nb) aux[t] = sd[t] - v;
}

// row_ptr[i] += aux[block(i)]; dinv[i] = rsqrt(1+cnt[i]); cnt[i] = 0 (reused as fill ctr)
__global__ void scanC_kernel(int* __restrict__ row_ptr, const int* __restrict__ aux,
                             int* __restrict__ cnt, float* __restrict__ dinv, int N, int E) {
    int i = blockIdx.x * blockDim.x + threadIdx.x;
    if (i < N) {
        row_ptr[i] += aux[i >> 10];
        int c = cnt[i];
        dinv[i] = rsqrtf(1.0f + (float)c);
        cnt[i] = 0;  // becomes the fill counter
    }
    if (i == 0) row_ptr[N] = E;
}

// csr_src[row_ptr[col]++] = row
__global__ void fill_kernel(const void* __restrict__ ei, const int* __restrict__ row_ptr,
                            int* __restrict__ fill, int* __restrict__ csr_src,
                            const int* __restrict__ flag, long long E) {
    long long e = (long long)blockIdx.x * blockDim.x + threadIdx.x;
    if (e >= E) return;
    int is32 = *flag;
    int r = (int)load_idx(ei, e, is32);
    int c = (int)load_idx(ei, E + e, is32);
    int pos = row_ptr[c] + atomicAdd(&fill[c], 1);
    csr_src[pos] = r;
}

// One wave per destination node, lane = feature. No atomics.
// hout[i][lane] = dinv[i]^2*hin[i][lane] + sum_k dinv[i]*dinv[s_k]*hin[s_k][lane]
__global__ void gather_kernel(const float* __restrict__ hin, float* __restrict__ hout,
                              const int* __restrict__ row_ptr, const int* __restrict__ csr_src,
                              const float* __restrict__ dinv, int N) {
    int t = blockIdx.x * blockDim.x + threadIdx.x;
    int node = t >> 6;
    int lane = t & 63;
    if (node >= N) return;
    int beg = row_ptr[node];
    int end = row_ptr[node + 1];
    float di = dinv[node];
    float acc = di * di * hin[node * NF + lane];
    for (int k = beg; k < end; ++k) {
        int s = csr_src[k];  // wave-uniform broadcast load
        acc += di * dinv[s] * hin[s * NF + lane];
    }
    hout[node * NF + lane] = acc;
}

// logits = h @ W^T + b ; relu ; log_softmax. Thread = node; LDS-staged coalesced writes.
__global__ void classify_kernel(const float* __restrict__ h, const float* __restrict__ W,
                                const float* __restrict__ b, float* __restrict__ out, int N) {
    __shared__ float4 sW[NC * (NF / 4)];
    __shared__ float sb[NC];
    __shared__ float sLg[256 * (NC + 1)];
    for (int i = threadIdx.x; i < NC * (NF / 4); i += blockDim.x)
        sW[i] = ((const float4*)W)[i];
    if (threadIdx.x < NC) sb[threadIdx.x] = b[threadIdx.x];
    __syncthreads();

    int base = blockIdx.x * 256;
    int node = base + threadIdx.x;
    if (node < N) {
        float4 hv[NF / 4];
        const float4* hp = (const float4*)(h + (long long)node * NF);
#pragma unroll
        for (int i = 0; i < NF / 4; ++i) hv[i] = hp[i];

        float lg[NC];
        float mx = 0.0f;  // post-relu values are >= 0
#pragma unroll
        for (int c = 0; c < NC; ++c) {
            float4 a = {0.f, 0.f, 0.f, 0.f};
#pragma unroll
            for (int i = 0; i < NF / 4; ++i) {
                float4 w = sW[c * (NF / 4) + i];
                a.x += w.x * hv[i].x;
                a.y += w.y * hv[i].y;
                a.z += w.z * hv[i].z;
                a.w += w.w * hv[i].w;
            }
            float l = (a.x + a.y) + (a.z + a.w) + sb[c];
            l = fmaxf(l, 0.0f);
            lg[c] = l;
            mx = fmaxf(mx, l);
        }
        float s = 0.0f;
#pragma unroll
        for (int c = 0; c < NC; ++c) s += __expf(lg[c] - mx);
        float lse = mx + __logf(s);
#pragma unroll
        for (int c = 0; c < NC; ++c) sLg[threadIdx.x * (NC + 1) + c] = lg[c] - lse;
    }
    __syncthreads();

    int nvalid = N - base;
    if (nvalid > 256) nvalid = 256;
    float* op = out + (long long)base * NC;
    for (int idx = threadIdx.x; idx < nvalid * NC; idx += 256) {
        int n = idx / NC;
        int c = idx - n * NC;
        op[idx] = sLg[n * (NC + 1) + c];
    }
}

extern "C" void kernel_launch(void* const* d_in, const int* in_sizes, int n_in,
                              void* d_out, int out_size, void* d_ws, size_t ws_size,
                              hipStream_t stream) {
    const float* x = (const float*)d_in[0];
    const void* ei = d_in[1];
    const float* W = (const float*)d_in[2];
    const float* b = (const float*)d_in[3];
    float* out = (float*)d_out;

    const int N = in_sizes[0] / NF;          // 100000
    const long long E = in_sizes[1] / 2;     // 1250000

    // workspace layout (256B aligned chunks)
    size_t off = 0;
    int* flag = (int*)((char*)d_ws + off);
    off += 256;
    int* cnt = (int*)((char*)d_ws + off);           // later reused as fill counters
    off += ((size_t)N * 4 + 255) & ~(size_t)255;
    int* row_ptr = (int*)((char*)d_ws + off);
    off += ((size_t)(N + 1) * 4 + 255) & ~(size_t)255;
    int* aux = (int*)((char*)d_ws + off);
    off += 1024;
    float* dinv = (float*)((char*)d_ws + off);
    off += ((size_t)N * 4 + 255) & ~(size_t)255;
    int* csr_src = (int*)((char*)d_ws + off);
    off += ((size_t)E * 4 + 255) & ~(size_t)255;
    float* h1 = (float*)((char*)d_ws + off);
    off += (size_t)N * NF * 4;
    float* h2 = (float*)((char*)d_ws + off);
    off += (size_t)N * NF * 4;
    if (off > ws_size) return;  // insufficient workspace

    const int B = 256;
    int gridN = (N + B - 1) / B;
    int gridE = (int)((E + B - 1) / B);
    int nScanBlocks = (N + SCAN_BLK - 1) / SCAN_BLK;  // 98

    // 0. dtype detection
    int n_check = (int)((E < 65536) ? E : 65536);
    detect_dtype_kernel<<<1, 256, 0, stream>>>((const unsigned int*)ei, flag, n_check);

    // 1. CSR build: count -> scan -> fill ; dinv from degrees
    zero_cnt_kernel<<<gridN, B, 0, stream>>>(cnt, N);
    count_kernel<<<gridE, B, 0, stream>>>(ei, cnt, flag, E);
    scanA_kernel<<<nScanBlocks, 256, 0, stream>>>(cnt, row_ptr, aux, N);
    scanB_kernel<<<1, 128, 0, stream>>>(aux, nScanBlocks);
    scanC_kernel<<<gridN, B, 0, stream>>>(row_ptr, aux, cnt, dinv, N, (int)E);
    fill_kernel<<<gridE, B, 0, stream>>>(ei, row_ptr, cnt, csr_src, flag, E);

    // 2. K=3 propagation hops, gather-based (no atomics)
    int gridG = (N * 64 + B - 1) / B;
    const float* hin = x;
    float* bufs[3] = {h1, h2, h1};
    for (int k = 0; k < 3; ++k) {
        float* hout = bufs[k];
        gather_kernel<<<gridG, B, 0, stream>>>(hin, hout, row_ptr, csr_src, dinv, N);
        hin = hout;
    }

    // 3. classify: linear + relu + log_softmax
    classify_kernel<<<gridN, B, 0, stream>>>(hin, W, b, out, N);
}